// Round 24
// baseline (53.408 us; speedup 1.0000x reference)
//
#include <hip/hip_runtime.h>

// Acrobot GN step — single-kernel version: gn_prep FOLDED into gn_main's init phase.
// R17..R23 post-mortem: six distinct scheduling optimizations all tie at 32.0us —
// gn_main is plateaued at the forced operating point (2 waves/SIMD @ 256 regs).
// The remaining identifiable cost is the serialized gn_prep kernel (~4-6us launch+work).
// Each block now builds its LDS weight tables directly from the raw f32 inputs
// (exact gn_prep formulas inline; L2-resident reads, parallel across blocks).
// Main loop = R23 verified body (dual row-groups + ping-pong fragment prefetch).
//   G1: e1 = relu(A1 @ in32)                 16 MFMA
//   G2: e2 = relu(A2 @ e1 + be2)             64 MFMA (A2 ping-pong from swizzled LDS)
//   G3: hdd = relu(A3 @ [e2[r^1]; sender,1]) 80 MFMA (A3 ping-pong from swizzled LDS)
//   G4: delta = A4 @ relu(hdd) + bn2         8 MFMA
// No barriers in loop; LDS 74KB -> 2 blocks/CU; grid 512 x 256thr; 4 tiles/wave.

typedef __attribute__((ext_vector_type(8))) short bf16x8;
typedef __attribute__((ext_vector_type(4))) float f32x4;

union U4B { uint4 u; bf16x8 b; };

__device__ __forceinline__ unsigned short f2bf(float f) {
  union { float f; unsigned u; } v; v.f = f;
  return (unsigned short)((v.u + 0x7FFFu + ((v.u >> 16) & 1u)) >> 16);  // RNE
}

__device__ __forceinline__ unsigned cvtpk(float lo, float hi) {
  unsigned r;
  asm("v_cvt_pk_bf16_f32 %0, %1, %2" : "=v"(r) : "v"(lo), "v"(hi));
  return r;
}

// K-dim permutation matching the in-register accumulator packing:
// B element position k=(kk,gg,i) holds feature 32*kk + 16*(i>>2) + 4*gg + (i&3).
__device__ __forceinline__ int kperm(int k) {
  int kk = k >> 5, gg = (k >> 3) & 3, i = k & 7;
  return kk * 32 + (i >> 2) * 16 + gg * 4 + (i & 3);
}

// ---------------- main fused kernel ----------------
#define WTILES 8192   // 262144 rows / 32 rows per wave-tile
#define NWAVES 2048   // 512 blocks x 4 waves; 4 tiles per wave

__global__ __launch_bounds__(256) __attribute__((amdgpu_waves_per_eu(2, 2)))
void gn_main(
    const float* __restrict__ x, const float* __restrict__ u,
    const float* __restrict__ nmean, const float* __restrict__ nstd,
    const float* __restrict__ emean, const float* __restrict__ estd,
    const float* __restrict__ We1, const float* __restrict__ be1,
    const float* __restrict__ We2, const float* __restrict__ be2,
    const float* __restrict__ Wn1, const float* __restrict__ bn1,
    const float* __restrict__ Wn2, const float* __restrict__ bn2,
    float* __restrict__ out)
{
  __shared__ __align__(16) unsigned short a2T[128 * 128];   // 32KB swizzled A2 table
  __shared__ __align__(16) unsigned short a3T[128 * 128];   // 32KB swizzled A3 table
  __shared__ __align__(16) unsigned short aLDS[4352];       // 8.5KB: A1c|A3e|A4|be2

  const int tid  = threadIdx.x;
  const int lane = tid & 63;
  const int wid  = tid >> 6;
  const int c15  = lane & 15;
  const int g    = lane >> 4;    // 0..3
  const int sw15 = (c15 & 7) << 4;

  // ---- build ALL weight tables directly from raw f32 inputs (gn_prep formulas) ----
  // a2T: A2 = We2^T, K-permuted, swizzled. a3T: A3 = Wn1[12:140]^T, K-permuted, swizzled.
  for (int t = tid; t < 2048; t += 256) {
    int j = t >> 4, c = t & 15;
    unsigned short s2[8], s3[8];
    #pragma unroll
    for (int i = 0; i < 8; ++i) {
      int kp = kperm(c * 8 + i);
      s2[i] = f2bf(We2[kp * 128 + j]);
      s3[i] = f2bf(Wn1[(12 + kp) * 128 + j]);
    }
    uint4 v2, v3;
    v2.x = (unsigned)s2[0] | ((unsigned)s2[1] << 16);
    v2.y = (unsigned)s2[2] | ((unsigned)s2[3] << 16);
    v2.z = (unsigned)s2[4] | ((unsigned)s2[5] << 16);
    v2.w = (unsigned)s2[6] | ((unsigned)s2[7] << 16);
    v3.x = (unsigned)s3[0] | ((unsigned)s3[1] << 16);
    v3.y = (unsigned)s3[2] | ((unsigned)s3[3] << 16);
    v3.z = (unsigned)s3[4] | ((unsigned)s3[5] << 16);
    v3.w = (unsigned)s3[6] | ((unsigned)s3[7] << 16);
    *(uint4*)((char*)a2T + j * 256 + ((c * 16) ^ ((j & 7) << 4))) = v2;
    *(uint4*)((char*)a3T + j * 256 + ((c * 16) ^ ((j & 7) << 4))) = v3;
  }
  // A1 compact [128j][8k]: k<7 -> We1 rows 10..16 ; k==7 -> be1
  for (int t = tid; t < 1024; t += 256) {
    int j = t >> 3, k = t & 7;
    aLDS[t] = f2bf((k < 7) ? We1[(10 + k) * 128 + j] : be1[j]);
  }
  // A3ext compact [128j][8c]: c0=Wn1r10, c1=Wn1r11, c2=bn1, rest 0
  for (int t = tid; t < 1024; t += 256) {
    int j = t >> 3, c = t & 7;
    float v = (c == 0) ? Wn1[10 * 128 + j] : (c == 1) ? Wn1[11 * 128 + j]
            : (c == 2) ? bn1[j] : 0.0f;
    aLDS[1024 + t] = f2bf(v);
  }
  // A4 = Wn2^T padded [16][128], K-permuted
  for (int t = tid; t < 2048; t += 256) {
    int jp = t >> 7, k = t & 127;
    aLDS[2048 + t] = f2bf((jp < 2) ? Wn2[kperm(k) * 2 + jp] : 0.0f);
  }
  // be2 as f32 at byte 8192
  if (tid < 128)
    ((float*)((char*)aLDS + 8192))[tid] = be2[tid];

  const float nm0 = nmean[0], nm1 = nmean[1];
  const float is0 = 1.0f / nstd[0], is1 = 1.0f / nstd[1];
  const float em0 = emean[0], ie0 = 1.0f / estd[0];
  const float cea1 = (0.0f - emean[1]) / estd[1];
  const float cea2 = (0.0f - emean[2]) / estd[2];
  const float bn20 = bn2[0], bn21 = bn2[1];
  const unsigned cpkw = cvtpk(cea2, 1.0f);   // B dword3: [cea2, 1.0]

  // tile-local B build (R19-verified): loads x/u, emits B fragment + sender pack + raw x
  auto buildB = [&](int wt_, int n_, unsigned& pks_, bf16x8& Bv_,
                    float& xs0_, float& xs1_) {
    float4 xv_ = (float4){0.f, 0.f, 0.f, 0.f};
    float  uv_ = 0.f;
    if (g == 0) {
      int b = wt_ * 16 + n_ * 8 + (c15 >> 1);
      xv_ = *(const float4*)(x + b * 4);
      uv_ = u[b];
    }
    xs0_ = (c15 & 1) ? xv_.y : xv_.x;   // this row's raw theta
    xs1_ = (c15 & 1) ? xv_.w : xv_.z;   // this row's raw v
    uint4 bu = (uint4){0u, 0u, 0u, 0u};
    if (g == 0) {                       // only k=0..7 nonzero; g==0 lanes hold them
      float a0 = (xv_.x - nm0) * is0, a1 = (xv_.z - nm1) * is1;   // node0
      float b0 = (xv_.y - nm0) * is0, b1 = (xv_.w - nm1) * is1;   // node1
      bool  e  = (c15 & 1);
      float s0 = e ? b0 : a0, s1 = e ? b1 : a1;   // sender feats
      float r0 = e ? a0 : b0, r1 = e ? a1 : b1;   // receiver feats
      float ea0 = (uv_ - em0) * ie0;
      bu.x = cvtpk(s0, s1); bu.y = cvtpk(r0, r1);
      bu.z = cvtpk(ea0, cea1); bu.w = cpkw;
    }
    pks_ = bu.x;
    U4B t; t.u = bu; Bv_ = t.b;
  };

  auto packE = [&](const f32x4 (&a)[2][8], bf16x8 (&E)[2][4]) {
    #pragma unroll
    for (int n = 0; n < 2; ++n)
      #pragma unroll
      for (int kk = 0; kk < 4; ++kk) {
        f32x4 a0 = a[n][2 * kk], a1 = a[n][2 * kk + 1];
        uint4 e;
        e.x = cvtpk(fmaxf(a0[0], 0.f), fmaxf(a0[1], 0.f));
        e.y = cvtpk(fmaxf(a0[2], 0.f), fmaxf(a0[3], 0.f));
        e.z = cvtpk(fmaxf(a1[0], 0.f), fmaxf(a1[1], 0.f));
        e.w = cvtpk(fmaxf(a1[2], 0.f), fmaxf(a1[3], 0.f));
        U4B t; t.u = e; E[n][kk] = t.b;
      }
  };
  auto packEswap = [&](const f32x4 (&a)[2][8], bf16x8 (&E)[2][4]) {
    #pragma unroll
    for (int n = 0; n < 2; ++n)
      #pragma unroll
      for (int kk = 0; kk < 4; ++kk) {
        f32x4 a0 = a[n][2 * kk], a1 = a[n][2 * kk + 1];
        uint4 e;
        e.x = __shfl_xor(cvtpk(fmaxf(a0[0], 0.f), fmaxf(a0[1], 0.f)), 1, 64);
        e.y = __shfl_xor(cvtpk(fmaxf(a0[2], 0.f), fmaxf(a0[3], 0.f)), 1, 64);
        e.z = __shfl_xor(cvtpk(fmaxf(a1[0], 0.f), fmaxf(a1[1], 0.f)), 1, 64);
        e.w = __shfl_xor(cvtpk(fmaxf(a1[2], 0.f), fmaxf(a1[3], 0.f)), 1, 64);
        U4B t; t.u = e; E[n][kk] = t.b;
      }
  };

  // K=128 layer with explicit ping-pong fragment prefetch (fA/fB, 64 regs)
  auto runLayer = [&](const char* base, const bf16x8 (&E)[2][4], f32x4 (&acc)[2][8]) {
    U4B fA[8], fB[8];
    #pragma unroll
    for (int m = 0; m < 8; ++m)         // kk=0 batch
      fA[m].u = *(const uint4*)(base + (m * 16 + c15) * 256 + ((g * 16) ^ sw15));
    #pragma unroll
    for (int m = 0; m < 8; ++m)         // kk=1 batch
      fB[m].u = *(const uint4*)(base + (m * 16 + c15) * 256 + ((64 + g * 16) ^ sw15));
    #pragma unroll
    for (int m = 0; m < 8; ++m)         // compute kk=0
      #pragma unroll
      for (int n = 0; n < 2; ++n)
        acc[n][m] = __builtin_amdgcn_mfma_f32_16x16x32_bf16(fA[m].b, E[n][0], acc[n][m], 0, 0, 0);
    #pragma unroll
    for (int m = 0; m < 8; ++m)         // kk=2 batch
      fA[m].u = *(const uint4*)(base + (m * 16 + c15) * 256 + ((128 + g * 16) ^ sw15));
    #pragma unroll
    for (int m = 0; m < 8; ++m)         // compute kk=1
      #pragma unroll
      for (int n = 0; n < 2; ++n)
        acc[n][m] = __builtin_amdgcn_mfma_f32_16x16x32_bf16(fB[m].b, E[n][1], acc[n][m], 0, 0, 0);
    #pragma unroll
    for (int m = 0; m < 8; ++m)         // kk=3 batch
      fB[m].u = *(const uint4*)(base + (m * 16 + c15) * 256 + ((192 + g * 16) ^ sw15));
    #pragma unroll
    for (int m = 0; m < 8; ++m)         // compute kk=2
      #pragma unroll
      for (int n = 0; n < 2; ++n)
        acc[n][m] = __builtin_amdgcn_mfma_f32_16x16x32_bf16(fA[m].b, E[n][2], acc[n][m], 0, 0, 0);
    #pragma unroll
    for (int m = 0; m < 8; ++m)         // compute kk=3
      #pragma unroll
      for (int n = 0; n < 2; ++n)
        acc[n][m] = __builtin_amdgcn_mfma_f32_16x16x32_bf16(fB[m].b, E[n][3], acc[n][m], 0, 0, 0);
  };

  __syncthreads();   // tables ready — the only barrier

  for (int wt = blockIdx.x * 4 + wid; wt < WTILES; wt += NWAVES) {
    const int rowbase = wt * 32;

    // opaque LDS offset: stop LICM/CSE from hoisting table reads across tiles
    unsigned aoff = 0;
    asm volatile("" : "+v"(aoff));
    const char* aB  = (const char*)aLDS + aoff;
    const char* a2B = (const char*)a2T + aoff;
    const char* a3B = (const char*)a3T + aoff;

    // ---------- A1 fragments issued first (latency overlaps buildB's VALU) ----------
    U4B A1t[8];
    #pragma unroll
    for (int m = 0; m < 8; ++m)
      A1t[m].u = *(const uint4*)(aB + (m * 16 + c15) * 16);

    // ---------- build B-operands for both row-groups (tile-local x/u loads) ----------
    unsigned pks[2]; bf16x8 Bv[2];
    float xs0[2], xs1[2];
    #pragma unroll
    for (int n = 0; n < 2; ++n)
      buildB(wt, n, pks[n], Bv[n], xs0[n], xs1[n]);

    f32x4 acc[2][8];

    // ---------- G1: e1 = relu(A1 @ in32) ----------
    #pragma unroll
    for (int m = 0; m < 8; ++m)
      #pragma unroll
      for (int n = 0; n < 2; ++n) {
        f32x4 z = (f32x4){0.f, 0.f, 0.f, 0.f};
        acc[n][m] = __builtin_amdgcn_mfma_f32_16x16x32_bf16(A1t[m].b, Bv[n], z, 0, 0, 0);
      }
    bf16x8 E1[2][4];
    packE(acc, E1);

    // ---------- G2: e2 = relu(A2 @ e1 + be2); ping-pong A2 fragments ----------
    #pragma unroll
    for (int m = 0; m < 8; ++m) {
      f32x4 bz = *(const f32x4*)(aB + 8192 + (m * 16 + g * 4) * 4);
      acc[0][m] = bz; acc[1][m] = bz;
    }
    runLayer(a2B, E1, acc);
    bf16x8 E2[2][4];
    packEswap(acc, E2);

    // ---------- G3: hdd = relu(A3 @ [e2[r^1]; sender,1]); ping-pong A3 ----------
    #pragma unroll
    for (int m = 0; m < 8; ++m) {
      acc[0][m] = (f32x4){0.f, 0.f, 0.f, 0.f};
      acc[1][m] = (f32x4){0.f, 0.f, 0.f, 0.f};
    }
    runLayer(a3B, E2, acc);
    {
      // K-chunk 4: node feats (= sender feats) + const-1 (bn1 column)
      U4B t4[2];
      #pragma unroll
      for (int n = 0; n < 2; ++n) {
        uint4 b4 = (uint4){0u, 0u, 0u, 0u};
        if (g == 0) { b4.x = pks[n]; b4.y = 0x00003F80u; }
        t4[n].u = b4;
      }
      #pragma unroll
      for (int m = 0; m < 8; ++m) {
        U4B te; te.u = *(const uint4*)(aB + 2048 + (m * 16 + c15) * 16);  // A3e frag
        #pragma unroll
        for (int n = 0; n < 2; ++n)
          acc[n][m] = __builtin_amdgcn_mfma_f32_16x16x32_bf16(te.b, t4[n].b, acc[n][m], 0, 0, 0);
      }
    }

    // ---------- G4: delta = A4 @ relu(hdd) + bn2; A4 from aLDS (4 reads) ----------
    {
      U4B A4f[4];
      #pragma unroll
      for (int kk = 0; kk < 4; ++kk)
        A4f[kk].u = *(const uint4*)(aB + 4096 + c15 * 256 + kk * 64 + g * 16);
      #pragma unroll
      for (int n = 0; n < 2; ++n) {
        bf16x8 HD[4];
        #pragma unroll
        for (int kk = 0; kk < 4; ++kk) {
          f32x4 a0 = acc[n][2 * kk], a1 = acc[n][2 * kk + 1];
          uint4 e;
          e.x = cvtpk(fmaxf(a0[0], 0.f), fmaxf(a0[1], 0.f));
          e.y = cvtpk(fmaxf(a0[2], 0.f), fmaxf(a0[3], 0.f));
          e.z = cvtpk(fmaxf(a1[0], 0.f), fmaxf(a1[1], 0.f));
          e.w = cvtpk(fmaxf(a1[2], 0.f), fmaxf(a1[3], 0.f));
          U4B t; t.u = e; HD[kk] = t.b;
        }
        f32x4 a4 = (f32x4){0.f, 0.f, 0.f, 0.f};
        #pragma unroll
        for (int kk = 0; kk < 4; ++kk)
          a4 = __builtin_amdgcn_mfma_f32_16x16x32_bf16(A4f[kk].b, HD[kk], a4, 0, 0, 0);
        if (g == 0) {                  // lane holds delta c0,c1 for row rowbase+n*16+c15
          int gr = rowbase + n * 16 + c15;
          int bidx = gr >> 1, k = gr & 1;
          out[bidx * 4 + k]     = xs0[n] + a4[0] + bn20;
          out[bidx * 4 + k + 2] = xs1[n] + a4[1] + bn21;
        }
      }
    }
    // no barrier: LDS tables are read-only after init; all activations in registers.
  }
}

extern "C" void kernel_launch(void* const* d_in, const int* in_sizes, int n_in,
                              void* d_out, int out_size, void* d_ws, size_t ws_size,
                              hipStream_t stream) {
  const float* x   = (const float*)d_in[0];
  const float* u   = (const float*)d_in[1];
  const float* nm  = (const float*)d_in[2];
  const float* ns  = (const float*)d_in[3];
  const float* em  = (const float*)d_in[4];
  const float* es  = (const float*)d_in[5];
  const float* We1 = (const float*)d_in[6];
  const float* be1 = (const float*)d_in[7];
  const float* We2 = (const float*)d_in[8];
  const float* be2 = (const float*)d_in[9];
  const float* Wn1 = (const float*)d_in[10];
  const float* bn1 = (const float*)d_in[11];
  const float* Wn2 = (const float*)d_in[12];
  const float* bn2 = (const float*)d_in[13];
  float* out = (float*)d_out;

  gn_main<<<512, 256, 0, stream>>>(x, u, nm, ns, em, es,
                                   We1, be1, We2, be2, Wn1, bn1, Wn2, bn2, out);
}